// Round 22
// baseline (259.083 us; speedup 1.0000x reference)
//
#include <hip/hip_runtime.h>
#include <hip/hip_fp16.h>

#define NN 100000
#define NE 1600000
#define NHEADS 4
#define WINSZ 12500             // NN / 8 dst-window per XCD
#define CAP 48                  // bucket capacity per node (deg ~ Poisson(16))
#define INV_LN2 1.4426950408889634f
#define NGRP 196                // fused groups of 40 blocks (32 build + 8 gemm)

typedef _Float16 f16x8 __attribute__((ext_vector_type(8)));
typedef float f32x4 __attribute__((ext_vector_type(4)));
typedef int i32x4 __attribute__((ext_vector_type(4)));

// ---------------------------------------------------------------------------
// Fused setup: deg=0, phantom als row, W -> transposed fp16 EXTENDED matrix:
//   rows 0..127   : Wt[j][k] = W[k][j]
//   rows 128..131 : INV_LN2 * (W @ a_src)[k][hd]
//   rows 132..135 : INV_LN2 * (W @ a_dst)[k][hd]
//   rows 136..143 : zero (unused cols of the 9th MFMA tile)
__global__ __launch_bounds__(256) void setup_kernel(
    const float* __restrict__ W1, const float* __restrict__ W2,
    const float* __restrict__ a_src1, const float* __restrict__ a_dst1,
    const float* __restrict__ a_src2, const float* __restrict__ a_dst2,
    __half* __restrict__ W1t, __half* __restrict__ W2t,
    int* __restrict__ deg, float* __restrict__ als)
{
    int i = blockIdx.x * 256 + threadIdx.x;
    if (i < NN) deg[i] = 0;
    if (i < 4) als[NN * 4 + i] = -1e30f;
    if (i < 16384) {
        int k = i >> 7, j = i & 127;
        W1t[j * 128 + k] = __float2half(W1[i]);
        W2t[j * 128 + k] = __float2half(W2[i]);
    }
    if (i >= 16384 && i < 18432) {              // Wa rows: 2 layers x 1024
        int t = i - 16384;
        int layer = t >> 10;
        int r = t & 1023;
        int sd = r >> 9;
        int hd = (r >> 7) & 3;
        int k  = r & 127;
        const float* W = layer ? W2 : W1;
        const float* a = layer ? (sd ? a_dst2 : a_src2)
                               : (sd ? a_dst1 : a_src1);
        float acc = 0.f;
#pragma unroll
        for (int c = 0; c < 32; ++c)
            acc = fmaf(W[k * 128 + hd * 32 + c], a[hd * 32 + c], acc);
        __half* Wt = layer ? W2t : W1t;
        Wt[(128 + sd * 4 + hd) * 128 + k] = __float2half(acc * INV_LN2);
    }
    if (i >= 18432 && i < 20480) {              // zero rows 136..143
        int r = i - 18432;
        int layer = r >> 10;
        int rr = r & 1023;
        (layer ? W2t : W1t)[136 * 128 + rr] = __float2half(0.f);
    }
}

// ---------------------------------------------------------------------------
// FUSED gemm1 + build, role-INTERLEAVED in groups of 40 blocks:
//   slot = (blockIdx%40)>>3 in 0..4, w = blockIdx&7 (40%8==0 keeps w == XCD).
//   slot 0..3 -> build (window w, chunk q*4+slot); slot 4 -> gemm tile q*8+w.
// At any instant the resident mix is ~80% latency-bound build waves + ~20%
// MFMA gemm waves -> uniform overlap.
__global__ __launch_bounds__(256) void fused_gb_kernel(
    const float* __restrict__ x, const __half* __restrict__ Wt,
    __half* __restrict__ h, float* __restrict__ als, float* __restrict__ ald,
    const int* __restrict__ ei, int* __restrict__ deg, int* __restrict__ bucket)
{
    const int q    = blockIdx.x / 40;
    const int r    = blockIdx.x % 40;
    const int slot = r >> 3;
    const int w    = r & 7;

    if (slot == 4) {
        // ---- gemm path: 16 rows per wave, 64 rows per block ----
        const int wave = threadIdx.x >> 6;
        const int l    = threadIdx.x & 63;
        const int lr   = l & 15;
        const int lk   = l >> 4;
        const int row  = (q * 8 + w) * 64 + wave * 16;
        if (row >= NN) return;

        f16x8 a[4];
#pragma unroll
        for (int kk = 0; kk < 4; ++kk) {
            const float4* p = reinterpret_cast<const float4*>(x + (row + lr) * 128 + kk * 32 + lk * 8);
            float4 u = p[0], v = p[1];
            f16x8 t;
            t[0] = (_Float16)u.x; t[1] = (_Float16)u.y; t[2] = (_Float16)u.z; t[3] = (_Float16)u.w;
            t[4] = (_Float16)v.x; t[5] = (_Float16)v.y; t[6] = (_Float16)v.z; t[7] = (_Float16)v.w;
            a[kk] = t;
        }

        f32x4 acc[9];
#pragma unroll
        for (int n = 0; n < 9; ++n) acc[n] = (f32x4)(0.f);
#pragma unroll
        for (int n = 0; n < 9; ++n) {
#pragma unroll
            for (int kk = 0; kk < 4; ++kk) {
                f16x8 b = *reinterpret_cast<const f16x8*>(Wt + (n * 16 + lr) * 128 + kk * 32 + lk * 8);
                acc[n] = __builtin_amdgcn_mfma_f32_16x16x32_f16(a[kk], b, acc[n], 0, 0, 0);
            }
        }
#pragma unroll
        for (int n = 0; n < 8; ++n) {
#pragma unroll
            for (int q2 = 0; q2 < 4; ++q2)
                h[(row + lk * 4 + q2) * 128 + n * 16 + lr] = __float2half(acc[n][q2]);
        }
        if (lr < 8) {
            const int hh = lr & 3;
            float* dst = (lr < 4) ? als : ald;
#pragma unroll
            for (int q2 = 0; q2 < 4; ++q2)
                dst[(row + lk * 4 + q2) * 4 + hh] = acc[8][q2];
        }
    } else {
        // ---- build path: dst-windowed, XCD-affine, pos-major bucket ----
        int base = (((q * 4 + slot) * 256) + threadIdx.x) * 8;
        if (base >= NE) return;
        i32x4 d4a = *reinterpret_cast<const i32x4*>(ei + NE + base);
        i32x4 d4b = *reinterpret_cast<const i32x4*>(ei + NE + base + 4);
        i32x4 s4a = *reinterpret_cast<const i32x4*>(ei + base);
        i32x4 s4b = *reinterpret_cast<const i32x4*>(ei + base + 4);
        int dd[8] = {d4a[0], d4a[1], d4a[2], d4a[3], d4b[0], d4b[1], d4b[2], d4b[3]};
        int ss[8] = {s4a[0], s4a[1], s4a[2], s4a[3], s4b[0], s4b[1], s4b[2], s4b[3]};
#pragma unroll
        for (int u = 0; u < 8; ++u) {
            int d = dd[u];
            if ((unsigned)(d - w * WINSZ) < (unsigned)WINSZ) {
                int pos = atomicAdd(&deg[d], 1);
                if (pos < CAP) bucket[pos * NN + d] = ss[u];   // overflow guard
            }
        }
    }
}

// ---------------------------------------------------------------------------
// Standalone MFMA GEMM for layer 2 (2-tile/wave, fp16 A), with logit columns.
__global__ __launch_bounds__(256) void gemm16_kernel(
    const __half* __restrict__ xh, const __half* __restrict__ Wt,
    __half* __restrict__ h, float* __restrict__ als, float* __restrict__ ald)
{
    const int wave = threadIdx.x >> 6;
    const int l    = threadIdx.x & 63;
    const int lr   = l & 15;
    const int lk   = l >> 4;

    const int row0 = blockIdx.x * 128 + wave * 16;
    const int row1 = row0 + 64;
    const bool t1 = (row1 < NN);
    if (row0 >= NN) return;

    f16x8 a0[4], a1[4];
#pragma unroll
    for (int kk = 0; kk < 4; ++kk)
        a0[kk] = *reinterpret_cast<const f16x8*>(xh + (row0 + lr) * 128 + kk * 32 + lk * 8);
    if (t1) {
#pragma unroll
        for (int kk = 0; kk < 4; ++kk)
            a1[kk] = *reinterpret_cast<const f16x8*>(xh + (row1 + lr) * 128 + kk * 32 + lk * 8);
    }

    f32x4 acc0[9], acc1[9];
#pragma unroll
    for (int n = 0; n < 9; ++n) { acc0[n] = (f32x4)(0.f); acc1[n] = (f32x4)(0.f); }

#pragma unroll
    for (int n = 0; n < 9; ++n) {
#pragma unroll
        for (int kk = 0; kk < 4; ++kk) {
            f16x8 b = *reinterpret_cast<const f16x8*>(Wt + (n * 16 + lr) * 128 + kk * 32 + lk * 8);
            acc0[n] = __builtin_amdgcn_mfma_f32_16x16x32_f16(a0[kk], b, acc0[n], 0, 0, 0);
            if (t1)
                acc1[n] = __builtin_amdgcn_mfma_f32_16x16x32_f16(a1[kk], b, acc1[n], 0, 0, 0);
        }
    }

#pragma unroll
    for (int n = 0; n < 8; ++n) {
#pragma unroll
        for (int q = 0; q < 4; ++q) {
            h[(row0 + lk * 4 + q) * 128 + n * 16 + lr] = __float2half(acc0[n][q]);
            if (t1)
                h[(row1 + lk * 4 + q) * 128 + n * 16 + lr] = __float2half(acc1[n][q]);
        }
    }
    if (lr < 8) {
        const int hh = lr & 3;
        float* dst = (lr < 4) ? als : ald;
#pragma unroll
        for (int q = 0; q < 4; ++q) {
            dst[(row0 + lk * 4 + q) * 4 + hh] = acc0[8][q];
            if (t1)
                dst[(row1 + lk * 4 + q) * 4 + hh] = acc1[8][q];
        }
    }
}

// ---------------------------------------------------------------------------
// Pad: write phantom node NN into slots [cnt, ceil8(cnt)); slots beyond are
// never read.
__global__ void pad_kernel(const int* __restrict__ deg, int* __restrict__ bucket)
{
    int node = blockIdx.x * 256 + threadIdx.x;
    if (node >= NN) return;
    int cnt = deg[node]; cnt = cnt < CAP ? cnt : CAP;
    int cnt8 = (cnt + 7) & ~7;
    for (int k = cnt; k < cnt8; ++k) bucket[k * NN + node] = NN;
}

// ---------------------------------------------------------------------------
// Gather-reduce: 4 nodes per wave, 16 lanes per node, 8 channels per lane.
// Block-local degree sort: wave 0 ranks the block's 16 nodes by trip count
// (descending, deterministic tie-break) and waves take rank quartiles, so the
// 4 nodes in lockstep per wave have similar loop bounds — cuts the max-of-4
// Poisson divergence inflation (~1.2x -> ~1.05x wave-cycles). Barriers are
// prologue-only (not the r8 inter-phase coupling pattern).
// mode 1: write relu(o) fp16 to yh (layer-1 mid). mode 0: write o fp32 to yf.
__global__ __launch_bounds__(256) void agg_kernel(
    const int* __restrict__ bucket, const int* __restrict__ deg,
    const float* __restrict__ als, const float* __restrict__ ald,
    const __half* __restrict__ h, const float* __restrict__ b,
    __half* __restrict__ yh, float* __restrict__ yf, int mode)
{
    __shared__ int ldsdeg[16];
    __shared__ int ldsord[16];

    const int lane = threadIdx.x & 63;
    const int wv   = threadIdx.x >> 6;
    const int g    = lane >> 4;
    const int l    = lane & 15;
    const int hd   = l >> 2;
    const int w    = blockIdx.x & 7;
    const int cbase = (blockIdx.x >> 3) * 16;     // node-offset base in window

    // ---- prologue: rank the block's 16 nodes by trip count ----
    if (threadIdx.x < 16) {
        int noff = cbase + threadIdx.x;
        int c = 0;
        if (noff < WINSZ) {
            c = deg[w * WINSZ + noff];
            c = c < CAP ? c : CAP;
            c = (c + 7) & ~7;
        }
        ldsdeg[threadIdx.x] = c;
    }
    __syncthreads();
    if (threadIdx.x < 16) {
        int my = ldsdeg[threadIdx.x];
        int rank = 0;
#pragma unroll
        for (int j = 0; j < 16; ++j) {
            int oj = ldsdeg[j];
            if (oj > my || (oj == my && j < (int)threadIdx.x)) ++rank;
        }
        ldsord[rank] = threadIdx.x;
    }
    __syncthreads();

    const int nodeoff = cbase + ldsord[wv * 4 + g];
    const bool valid = nodeoff < WINSZ;           // NN == 8*WINSZ exactly
    int node = valid ? (w * WINSZ + nodeoff) : (NN - 1);

    int cnt = deg[node]; cnt = cnt < CAP ? cnt : CAP;
    const int cnt8 = valid ? ((cnt + 7) & ~7) : 0;
    const int* __restrict__ lstT = bucket + node;
    const float ad = ald[node * 4 + hd];
    const f16x8* __restrict__ h8 = reinterpret_cast<const f16x8*>(h);

    float acc[8];
#pragma unroll
    for (int c = 0; c < 8; ++c) acc[c] = 0.f;
    float den = 0.f;

    for (int k = 0; k < cnt8; k += 8) {
        int s[8];
#pragma unroll
        for (int u = 0; u < 8; ++u) s[u] = lstT[(k + u) * NN];
        float wt[8]; f16x8 hv[8];
#pragma unroll
        for (int u = 0; u < 8; ++u) {
            float v = als[s[u] * 4 + hd] + ad;
            v = fmaxf(v, 0.2f * v);
            wt[u] = __builtin_amdgcn_exp2f(v);     // phantom slots -> 0
            hv[u] = h8[s[u] * 16 + l];
        }
#pragma unroll
        for (int u = 0; u < 8; ++u) {
            den += wt[u];
#pragma unroll
            for (int c = 0; c < 8; ++c)
                acc[c] = fmaf(wt[u], (float)hv[u][c], acc[c]);
        }
    }

    if (!valid) return;
    float inv = den > 0.f ? __frcp_rn(den) : 0.f;
    float4 b0 = *reinterpret_cast<const float4*>(b + l * 8);
    float4 b1 = *reinterpret_cast<const float4*>(b + l * 8 + 4);
    float o[8];
    o[0] = acc[0] * inv + b0.x; o[1] = acc[1] * inv + b0.y;
    o[2] = acc[2] * inv + b0.z; o[3] = acc[3] * inv + b0.w;
    o[4] = acc[4] * inv + b1.x; o[5] = acc[5] * inv + b1.y;
    o[6] = acc[6] * inv + b1.z; o[7] = acc[7] * inv + b1.w;
    if (mode) {
        f16x8 rr;
#pragma unroll
        for (int c = 0; c < 8; ++c) rr[c] = (_Float16)fmaxf(o[c], 0.f);
        *reinterpret_cast<f16x8*>(yh + node * 128 + l * 8) = rr;
    } else {
        float* p = yf + node * 128 + l * 8;
        *reinterpret_cast<float4*>(p)     = make_float4(o[0], o[1], o[2], o[3]);
        *reinterpret_cast<float4*>(p + 4) = make_float4(o[4], o[5], o[6], o[7]);
    }
}

// ---------------------------------------------------------------------------
extern "C" void kernel_launch(void* const* d_in, const int* in_sizes, int n_in,
                              void* d_out, int out_size, void* d_ws, size_t ws_size,
                              hipStream_t stream) {
    const float* x      = (const float*)d_in[0];
    const int*   ei     = (const int*)  d_in[1];
    const float* W1     = (const float*)d_in[2];
    const float* a_src1 = (const float*)d_in[3];
    const float* a_dst1 = (const float*)d_in[4];
    const float* b1     = (const float*)d_in[5];
    const float* W2     = (const float*)d_in[6];
    const float* a_src2 = (const float*)d_in[7];
    const float* a_dst2 = (const float*)d_in[8];
    const float* b2     = (const float*)d_in[9];

    char* ws = (char*)d_ws;
    __half* h       = (__half*)ws;                ws += sizeof(__half) * (NN + 1) * 128;
    __half* y1h     = (__half*)ws;                ws += sizeof(__half) * NN * 128;
    __half* W1t     = (__half*)ws;                ws += sizeof(__half) * 144 * 128;
    __half* W2t     = (__half*)ws;                ws += sizeof(__half) * 144 * 128;
    float* als      = (float*)ws;                 ws += sizeof(float) * (NN + 1) * 4;
    float* ald      = (float*)ws;                 ws += sizeof(float) * NN * 4;
    int*   deg      = (int*)ws;                   ws += sizeof(int) * NN;
    int*   bucket   = (int*)ws;                   ws += sizeof(int) * NN * CAP;
    float* out      = (float*)d_out;

    const int fused_grid = NGRP * 40;             // 7840: 6272 build + 1568 gemm
    const int gemm_grid  = (NN + 127) / 128;
    const int agg_grid   = 8 * ((WINSZ + 15) / 16);
    const int nb         = (NN + 255) / 256;

    // ---- setup, then role-interleaved {gemm1 | build}, then pad ----
    setup_kernel<<<nb, 256, 0, stream>>>(W1, W2, a_src1, a_dst1, a_src2, a_dst2,
                                         W1t, W2t, deg, als);
    fused_gb_kernel<<<fused_grid, 256, 0, stream>>>(x, W1t, h, als, ald,
                                                    ei, deg, bucket);
    pad_kernel<<<nb, 256, 0, stream>>>(deg, bucket);

    // ---- layer 1 aggregate ----
    agg_kernel<<<agg_grid, 256, 0, stream>>>(bucket, deg, als, ald, h, b1,
                                             y1h, nullptr, 1);

    // ---- layer 2 ----
    gemm16_kernel<<<gemm_grid, 256, 0, stream>>>(y1h, W2t, h, als, ald);
    agg_kernel<<<agg_grid, 256, 0, stream>>>(bucket, deg, als, ald, h, b2,
                                             nullptr, out, 0);
}

// Round 23
// 256.886 us; speedup vs baseline: 1.0086x; 1.0086x over previous
//
#include <hip/hip_runtime.h>
#include <hip/hip_fp16.h>

#define NN 100000
#define NE 1600000
#define NHEADS 4
#define WINSZ 12500             // NN / 8 dst-window per XCD
#define CAP 48                  // bucket capacity per node (deg ~ Poisson(16))
#define INV_LN2 1.4426950408889634f
#define NGRP 196                // fused groups of 40 blocks (32 build + 8 gemm)

typedef _Float16 f16x8 __attribute__((ext_vector_type(8)));
typedef float f32x4 __attribute__((ext_vector_type(4)));
typedef int i32x4 __attribute__((ext_vector_type(4)));

// ---------------------------------------------------------------------------
// Fused setup: deg=0, phantom als row, W -> transposed fp16 EXTENDED matrix:
//   rows 0..127   : Wt[j][k] = W[k][j]
//   rows 128..131 : INV_LN2 * (W @ a_src)[k][hd]
//   rows 132..135 : INV_LN2 * (W @ a_dst)[k][hd]
//   rows 136..143 : zero (unused cols of the 9th MFMA tile)
__global__ __launch_bounds__(256) void setup_kernel(
    const float* __restrict__ W1, const float* __restrict__ W2,
    const float* __restrict__ a_src1, const float* __restrict__ a_dst1,
    const float* __restrict__ a_src2, const float* __restrict__ a_dst2,
    __half* __restrict__ W1t, __half* __restrict__ W2t,
    int* __restrict__ deg, float* __restrict__ als)
{
    int i = blockIdx.x * 256 + threadIdx.x;
    if (i < NN) deg[i] = 0;
    if (i < 4) als[NN * 4 + i] = -1e30f;
    if (i < 16384) {
        int k = i >> 7, j = i & 127;
        W1t[j * 128 + k] = __float2half(W1[i]);
        W2t[j * 128 + k] = __float2half(W2[i]);
    }
    if (i >= 16384 && i < 18432) {              // Wa rows: 2 layers x 1024
        int t = i - 16384;
        int layer = t >> 10;
        int r = t & 1023;
        int sd = r >> 9;
        int hd = (r >> 7) & 3;
        int k  = r & 127;
        const float* W = layer ? W2 : W1;
        const float* a = layer ? (sd ? a_dst2 : a_src2)
                               : (sd ? a_dst1 : a_src1);
        float acc = 0.f;
#pragma unroll
        for (int c = 0; c < 32; ++c)
            acc = fmaf(W[k * 128 + hd * 32 + c], a[hd * 32 + c], acc);
        __half* Wt = layer ? W2t : W1t;
        Wt[(128 + sd * 4 + hd) * 128 + k] = __float2half(acc * INV_LN2);
    }
    if (i >= 18432 && i < 20480) {              // zero rows 136..143
        int r = i - 18432;
        int layer = r >> 10;
        int rr = r & 1023;
        (layer ? W2t : W1t)[136 * 128 + rr] = __float2half(0.f);
    }
}

// ---------------------------------------------------------------------------
// FUSED gemm1 + build, role-INTERLEAVED in groups of 40 blocks:
//   slot = (blockIdx%40)>>3 in 0..4, w = blockIdx&7 (40%8==0 keeps w == XCD).
//   slot 0..3 -> build (window w, chunk q*4+slot); slot 4 -> gemm tile q*8+w.
// At any instant the resident mix is ~80% latency-bound build waves + ~20%
// MFMA gemm waves -> uniform overlap.
__global__ __launch_bounds__(256) void fused_gb_kernel(
    const float* __restrict__ x, const __half* __restrict__ Wt,
    __half* __restrict__ h, float* __restrict__ als, float* __restrict__ ald,
    const int* __restrict__ ei, int* __restrict__ deg, int* __restrict__ bucket)
{
    const int q    = blockIdx.x / 40;
    const int r    = blockIdx.x % 40;
    const int slot = r >> 3;
    const int w    = r & 7;

    if (slot == 4) {
        // ---- gemm path: 16 rows per wave, 64 rows per block ----
        const int wave = threadIdx.x >> 6;
        const int l    = threadIdx.x & 63;
        const int lr   = l & 15;
        const int lk   = l >> 4;
        const int row  = (q * 8 + w) * 64 + wave * 16;
        if (row >= NN) return;

        f16x8 a[4];
#pragma unroll
        for (int kk = 0; kk < 4; ++kk) {
            const float4* p = reinterpret_cast<const float4*>(x + (row + lr) * 128 + kk * 32 + lk * 8);
            float4 u = p[0], v = p[1];
            f16x8 t;
            t[0] = (_Float16)u.x; t[1] = (_Float16)u.y; t[2] = (_Float16)u.z; t[3] = (_Float16)u.w;
            t[4] = (_Float16)v.x; t[5] = (_Float16)v.y; t[6] = (_Float16)v.z; t[7] = (_Float16)v.w;
            a[kk] = t;
        }

        f32x4 acc[9];
#pragma unroll
        for (int n = 0; n < 9; ++n) acc[n] = (f32x4)(0.f);
#pragma unroll
        for (int n = 0; n < 9; ++n) {
#pragma unroll
            for (int kk = 0; kk < 4; ++kk) {
                f16x8 b = *reinterpret_cast<const f16x8*>(Wt + (n * 16 + lr) * 128 + kk * 32 + lk * 8);
                acc[n] = __builtin_amdgcn_mfma_f32_16x16x32_f16(a[kk], b, acc[n], 0, 0, 0);
            }
        }
#pragma unroll
        for (int n = 0; n < 8; ++n) {
#pragma unroll
            for (int q2 = 0; q2 < 4; ++q2)
                h[(row + lk * 4 + q2) * 128 + n * 16 + lr] = __float2half(acc[n][q2]);
        }
        if (lr < 8) {
            const int hh = lr & 3;
            float* dst = (lr < 4) ? als : ald;
#pragma unroll
            for (int q2 = 0; q2 < 4; ++q2)
                dst[(row + lk * 4 + q2) * 4 + hh] = acc[8][q2];
        }
    } else {
        // ---- build path: dst-windowed, XCD-affine, pos-major bucket ----
        int base = (((q * 4 + slot) * 256) + threadIdx.x) * 8;
        if (base >= NE) return;
        i32x4 d4a = *reinterpret_cast<const i32x4*>(ei + NE + base);
        i32x4 d4b = *reinterpret_cast<const i32x4*>(ei + NE + base + 4);
        i32x4 s4a = *reinterpret_cast<const i32x4*>(ei + base);
        i32x4 s4b = *reinterpret_cast<const i32x4*>(ei + base + 4);
        int dd[8] = {d4a[0], d4a[1], d4a[2], d4a[3], d4b[0], d4b[1], d4b[2], d4b[3]};
        int ss[8] = {s4a[0], s4a[1], s4a[2], s4a[3], s4b[0], s4b[1], s4b[2], s4b[3]};
#pragma unroll
        for (int u = 0; u < 8; ++u) {
            int d = dd[u];
            if ((unsigned)(d - w * WINSZ) < (unsigned)WINSZ) {
                int pos = atomicAdd(&deg[d], 1);
                if (pos < CAP) bucket[pos * NN + d] = ss[u];   // overflow guard
            }
        }
    }
}

// ---------------------------------------------------------------------------
// Standalone MFMA GEMM for layer 2 (2-tile/wave, fp16 A), with logit columns.
__global__ __launch_bounds__(256) void gemm16_kernel(
    const __half* __restrict__ xh, const __half* __restrict__ Wt,
    __half* __restrict__ h, float* __restrict__ als, float* __restrict__ ald)
{
    const int wave = threadIdx.x >> 6;
    const int l    = threadIdx.x & 63;
    const int lr   = l & 15;
    const int lk   = l >> 4;

    const int row0 = blockIdx.x * 128 + wave * 16;
    const int row1 = row0 + 64;
    const bool t1 = (row1 < NN);
    if (row0 >= NN) return;

    f16x8 a0[4], a1[4];
#pragma unroll
    for (int kk = 0; kk < 4; ++kk)
        a0[kk] = *reinterpret_cast<const f16x8*>(xh + (row0 + lr) * 128 + kk * 32 + lk * 8);
    if (t1) {
#pragma unroll
        for (int kk = 0; kk < 4; ++kk)
            a1[kk] = *reinterpret_cast<const f16x8*>(xh + (row1 + lr) * 128 + kk * 32 + lk * 8);
    }

    f32x4 acc0[9], acc1[9];
#pragma unroll
    for (int n = 0; n < 9; ++n) { acc0[n] = (f32x4)(0.f); acc1[n] = (f32x4)(0.f); }

#pragma unroll
    for (int n = 0; n < 9; ++n) {
#pragma unroll
        for (int kk = 0; kk < 4; ++kk) {
            f16x8 b = *reinterpret_cast<const f16x8*>(Wt + (n * 16 + lr) * 128 + kk * 32 + lk * 8);
            acc0[n] = __builtin_amdgcn_mfma_f32_16x16x32_f16(a0[kk], b, acc0[n], 0, 0, 0);
            if (t1)
                acc1[n] = __builtin_amdgcn_mfma_f32_16x16x32_f16(a1[kk], b, acc1[n], 0, 0, 0);
        }
    }

#pragma unroll
    for (int n = 0; n < 8; ++n) {
#pragma unroll
        for (int q = 0; q < 4; ++q) {
            h[(row0 + lk * 4 + q) * 128 + n * 16 + lr] = __float2half(acc0[n][q]);
            if (t1)
                h[(row1 + lk * 4 + q) * 128 + n * 16 + lr] = __float2half(acc1[n][q]);
        }
    }
    if (lr < 8) {
        const int hh = lr & 3;
        float* dst = (lr < 4) ? als : ald;
#pragma unroll
        for (int q = 0; q < 4; ++q) {
            dst[(row0 + lk * 4 + q) * 4 + hh] = acc0[8][q];
            if (t1)
                dst[(row1 + lk * 4 + q) * 4 + hh] = acc1[8][q];
        }
    }
}

// ---------------------------------------------------------------------------
// Pad: write phantom node NN into slots [cnt, ceil8(cnt)); slots beyond are
// never read.
__global__ void pad_kernel(const int* __restrict__ deg, int* __restrict__ bucket)
{
    int node = blockIdx.x * 256 + threadIdx.x;
    if (node >= NN) return;
    int cnt = deg[node]; cnt = cnt < CAP ? cnt : CAP;
    int cnt8 = (cnt + 7) & ~7;
    for (int k = cnt; k < cnt8; ++k) bucket[k * NN + node] = NN;
}

// ---------------------------------------------------------------------------
// Gather-reduce: 4 nodes per wave, 16 lanes per node, 8 channels per lane.
// mode 1: write relu(o) fp16 to yh (layer-1 mid). mode 0: write o fp32 to yf.
__global__ __launch_bounds__(256) void agg_kernel(
    const int* __restrict__ bucket, const int* __restrict__ deg,
    const float* __restrict__ als, const float* __restrict__ ald,
    const __half* __restrict__ h, const float* __restrict__ b,
    __half* __restrict__ yh, float* __restrict__ yf, int mode)
{
    const int lane = threadIdx.x & 63;
    const int wv   = threadIdx.x >> 6;
    const int g    = lane >> 4;
    const int l    = lane & 15;
    const int hd   = l >> 2;

    int node = (blockIdx.x & 7) * WINSZ + (blockIdx.x >> 3) * 16 + wv * 4 + g;
    const bool valid = node < NN;
    if (!valid) node = NN - 1;

    int cnt = deg[node]; cnt = cnt < CAP ? cnt : CAP;
    const int cnt8 = valid ? ((cnt + 7) & ~7) : 0;
    const int* __restrict__ lstT = bucket + node;
    const float ad = ald[node * 4 + hd];
    const f16x8* __restrict__ h8 = reinterpret_cast<const f16x8*>(h);

    float acc[8];
#pragma unroll
    for (int c = 0; c < 8; ++c) acc[c] = 0.f;
    float den = 0.f;

    for (int k = 0; k < cnt8; k += 8) {
        int s[8];
#pragma unroll
        for (int u = 0; u < 8; ++u) s[u] = lstT[(k + u) * NN];
        float w[8]; f16x8 hv[8];
#pragma unroll
        for (int u = 0; u < 8; ++u) {
            float v = als[s[u] * 4 + hd] + ad;
            v = fmaxf(v, 0.2f * v);
            w[u] = __builtin_amdgcn_exp2f(v);      // phantom slots -> 0
            hv[u] = h8[s[u] * 16 + l];
        }
#pragma unroll
        for (int u = 0; u < 8; ++u) {
            den += w[u];
#pragma unroll
            for (int c = 0; c < 8; ++c)
                acc[c] = fmaf(w[u], (float)hv[u][c], acc[c]);
        }
    }

    if (!valid) return;
    float inv = den > 0.f ? __frcp_rn(den) : 0.f;
    float4 b0 = *reinterpret_cast<const float4*>(b + l * 8);
    float4 b1 = *reinterpret_cast<const float4*>(b + l * 8 + 4);
    float o[8];
    o[0] = acc[0] * inv + b0.x; o[1] = acc[1] * inv + b0.y;
    o[2] = acc[2] * inv + b0.z; o[3] = acc[3] * inv + b0.w;
    o[4] = acc[4] * inv + b1.x; o[5] = acc[5] * inv + b1.y;
    o[6] = acc[6] * inv + b1.z; o[7] = acc[7] * inv + b1.w;
    if (mode) {
        f16x8 rr;
#pragma unroll
        for (int c = 0; c < 8; ++c) rr[c] = (_Float16)fmaxf(o[c], 0.f);
        *reinterpret_cast<f16x8*>(yh + node * 128 + l * 8) = rr;
    } else {
        float* p = yf + node * 128 + l * 8;
        *reinterpret_cast<float4*>(p)     = make_float4(o[0], o[1], o[2], o[3]);
        *reinterpret_cast<float4*>(p + 4) = make_float4(o[4], o[5], o[6], o[7]);
    }
}

// ---------------------------------------------------------------------------
extern "C" void kernel_launch(void* const* d_in, const int* in_sizes, int n_in,
                              void* d_out, int out_size, void* d_ws, size_t ws_size,
                              hipStream_t stream) {
    const float* x      = (const float*)d_in[0];
    const int*   ei     = (const int*)  d_in[1];
    const float* W1     = (const float*)d_in[2];
    const float* a_src1 = (const float*)d_in[3];
    const float* a_dst1 = (const float*)d_in[4];
    const float* b1     = (const float*)d_in[5];
    const float* W2     = (const float*)d_in[6];
    const float* a_src2 = (const float*)d_in[7];
    const float* a_dst2 = (const float*)d_in[8];
    const float* b2     = (const float*)d_in[9];

    char* ws = (char*)d_ws;
    __half* h       = (__half*)ws;                ws += sizeof(__half) * (NN + 1) * 128;
    __half* y1h     = (__half*)ws;                ws += sizeof(__half) * NN * 128;
    __half* W1t     = (__half*)ws;                ws += sizeof(__half) * 144 * 128;
    __half* W2t     = (__half*)ws;                ws += sizeof(__half) * 144 * 128;
    float* als      = (float*)ws;                 ws += sizeof(float) * (NN + 1) * 4;
    float* ald      = (float*)ws;                 ws += sizeof(float) * NN * 4;
    int*   deg      = (int*)ws;                   ws += sizeof(int) * NN;
    int*   bucket   = (int*)ws;                   ws += sizeof(int) * NN * CAP;
    float* out      = (float*)d_out;

    const int fused_grid = NGRP * 40;             // 7840: 6272 build + 1568 gemm
    const int gemm_grid  = (NN + 127) / 128;
    const int agg_grid   = 8 * ((WINSZ + 15) / 16);
    const int nb         = (NN + 255) / 256;

    // ---- setup, then role-interleaved {gemm1 | build}, then pad ----
    setup_kernel<<<nb, 256, 0, stream>>>(W1, W2, a_src1, a_dst1, a_src2, a_dst2,
                                         W1t, W2t, deg, als);
    fused_gb_kernel<<<fused_grid, 256, 0, stream>>>(x, W1t, h, als, ald,
                                                    ei, deg, bucket);
    pad_kernel<<<nb, 256, 0, stream>>>(deg, bucket);

    // ---- layer 1 aggregate ----
    agg_kernel<<<agg_grid, 256, 0, stream>>>(bucket, deg, als, ald, h, b1,
                                             y1h, nullptr, 1);

    // ---- layer 2 ----
    gemm16_kernel<<<gemm_grid, 256, 0, stream>>>(y1h, W2t, h, als, ald);
    agg_kernel<<<agg_grid, 256, 0, stream>>>(bucket, deg, als, ald, h, b2,
                                             nullptr, out, 0);
}